// Round 1
// baseline (645.947 us; speedup 1.0000x reference)
//
#include <hip/hip_runtime.h>

// Scaled dot-product attention, B=8 H=12 S=1024 D=64, fp32 in/out.
// Outputs (concatenated in d_out): probs (B,H,S,S) then context (B,H,S,D).
// One 512-thread block per (bh, 64-row Q tile). bf16 MFMA for QK^T and PV.
//
// v2 changes (bank-conflict elimination + latency hiding):
//  - Key-permuted storage sigma(k) = (k&15)*8 + (k>>4) within each 128-key
//    span, applied to BOTH the P (A-operand) and V^T (B-operand) LDS tiles.
//    MFMA contracts over k-slots, so any slot->key map is legal if both
//    operands agree. This turns the 128 scalar bf16 probs->LDS writes into
//    16 ds_write_b128 (bank-balanced: 8 dw/bank = ideal), keeps all PV
//    fragment reads contiguous b128 (also exactly bank-balanced), and the
//    V^T staging writes become 64-lanes-one-row scalars (~2-way, vs the
//    old 8-way 4-row-stride pattern that no aligned pad could fix).
//  - PV chunks widened 64->128 keys: 16 barriers instead of 32.
//  - V prefetch issued AFTER the staging barrier so the loads overlap the
//    MFMA block instead of being drained by the barrier's vmcnt(0).
//  - Probs/context global stores are nontemporal (write-only stream,
//    403 MB): avoids RFO fetch + L2 thrash of the cached K/V.

#define SLEN 1024
#define DHEAD 64
#define NBH 96

typedef __attribute__((ext_vector_type(4))) float f32x4;
typedef __attribute__((ext_vector_type(8))) __bf16 bf16x8;

#define PL_STRIDE 1032   // 1024 + 8: row bytes 2064 = 129*16 (b128-aligned), 516 dw % 32 = 4
#define QT_STRIDE 72     // 64 + 8
#define VT_STRIDE 136    // 128 + 8: row bytes 272 = 17*16, 68 dw % 32 = 4

struct SMem {
  __bf16 pl[64][PL_STRIDE];     // probs bf16, key-permuted columns; 132096 B
  union {
    __bf16 qt[64][QT_STRIDE];   // scaled Q tile (phase 1)
    __bf16 vt[64][VT_STRIDE];   // V^T span: vt[d][sigma(k)] (phase 4)
  } u;                          // 17408 B
  float red[8][64];             // per-wave softmax partials
  float mrow[64];
  float invrow[64];
};                              // total ~152.1 KB < 160 KB

__global__ __launch_bounds__(512, 2)
void attn_fused(const float* __restrict__ Qp, const float* __restrict__ Kp,
                const float* __restrict__ Vp, const int* __restrict__ scale_p,
                float* __restrict__ out) {
  __shared__ SMem sm;
  const int tid  = threadIdx.x;
  const int w    = tid >> 6;     // wave 0..7
  const int lane = tid & 63;
  const int quad = lane >> 4;
  const int c16  = lane & 15;
  const int bh   = blockIdx.y;
  const int qbase = blockIdx.x * 64;

  // scale arrives as a 1-element array; robust to int32 or fp32 encoding
  int siv = *scale_p;
  float fs = (siv >= 1 && siv <= (1 << 24)) ? (float)siv : __int_as_float(siv);
  const float inv_scale = 1.0f / fs;

  const float* Qg = Qp + ((size_t)bh * SLEN + qbase) * DHEAD;
  const float* Kg = Kp + (size_t)bh * SLEN * DHEAD;
  const float* Vg = Vp + (size_t)bh * SLEN * DHEAD;

  // ---- stage Q tile (x 1/scale) to LDS as bf16 ----
  #pragma unroll
  for (int it = 0; it < 2; ++it) {
    int flat = it * 2048 + tid * 4;
    int r = flat >> 6, d = flat & 63;
    f32x4 qv = *(const f32x4*)(Qg + (size_t)r * DHEAD + d);
    #pragma unroll
    for (int j = 0; j < 4; ++j)
      sm.u.qt[r][d + j] = (__bf16)(qv[j] * inv_scale);
  }
  __syncthreads();

  // A-frags: A[m=lane&15][k=quad*8+j]
  bf16x8 af[4][2];
  #pragma unroll
  for (int rt = 0; rt < 4; ++rt)
    #pragma unroll
    for (int k0 = 0; k0 < 2; ++k0)
      af[rt][k0] = *(const bf16x8*)&sm.u.qt[rt * 16 + c16][k0 * 32 + quad * 8];

  f32x4 acc[4][8];
  {
    f32x4 z = {0.0f, 0.0f, 0.0f, 0.0f};
    #pragma unroll
    for (int rt = 0; rt < 4; ++rt)
      #pragma unroll
      for (int ct = 0; ct < 8; ++ct) acc[rt][ct] = z;
  }

  // ---- phase 1: S = (Q/scale) K^T.  Wave w owns key columns [w*128, w*128+128) ----
  #pragma unroll
  for (int ct = 0; ct < 8; ++ct) {
    int krow = w * 128 + ct * 16 + c16;   // B-frag: B[k=quad*8+j][n=lane&15] = K[n][k]
    const float* kr = Kg + (size_t)krow * DHEAD + quad * 8;
    f32x4 k0a = *(const f32x4*)(kr);
    f32x4 k0b = *(const f32x4*)(kr + 4);
    f32x4 k1a = *(const f32x4*)(kr + 32);
    f32x4 k1b = *(const f32x4*)(kr + 36);
    bf16x8 b0, b1;
    #pragma unroll
    for (int j = 0; j < 4; ++j) {
      b0[j]     = (__bf16)k0a[j];
      b0[j + 4] = (__bf16)k0b[j];
      b1[j]     = (__bf16)k1a[j];
      b1[j + 4] = (__bf16)k1b[j];
    }
    #pragma unroll
    for (int rt = 0; rt < 4; ++rt) {
      acc[rt][ct] = __builtin_amdgcn_mfma_f32_16x16x32_bf16(af[rt][0], b0, acc[rt][ct], 0, 0, 0);
      acc[rt][ct] = __builtin_amdgcn_mfma_f32_16x16x32_bf16(af[rt][1], b1, acc[rt][ct], 0, 0, 0);
    }
  }

  // ---- softmax: row max (C/D layout: row = rt*16 + quad*4 + reg, col = lane&15) ----
  float mx[4][4];
  #pragma unroll
  for (int rt = 0; rt < 4; ++rt)
    #pragma unroll
    for (int i = 0; i < 4; ++i) {
      float m = acc[rt][0][i];
      #pragma unroll
      for (int ct = 1; ct < 8; ++ct) m = fmaxf(m, acc[rt][ct][i]);
      mx[rt][i] = m;
    }
  #pragma unroll
  for (int off = 1; off < 16; off <<= 1)
    #pragma unroll
    for (int rt = 0; rt < 4; ++rt)
      #pragma unroll
      for (int i = 0; i < 4; ++i)
        mx[rt][i] = fmaxf(mx[rt][i], __shfl_xor(mx[rt][i], off));
  if (c16 == 0) {
    #pragma unroll
    for (int rt = 0; rt < 4; ++rt)
      #pragma unroll
      for (int i = 0; i < 4; ++i)
        sm.red[w][rt * 16 + quad * 4 + i] = mx[rt][i];
  }
  __syncthreads();
  if (tid < 64) {
    float m = sm.red[0][tid];
    #pragma unroll
    for (int w2 = 1; w2 < 8; ++w2) m = fmaxf(m, sm.red[w2][tid]);
    sm.mrow[tid] = m;
  }
  __syncthreads();

  // ---- exp + row sum ----
  float sum4[4][4];
  #pragma unroll
  for (int rt = 0; rt < 4; ++rt)
    #pragma unroll
    for (int i = 0; i < 4; ++i) {
      float m = sm.mrow[rt * 16 + quad * 4 + i];
      float s = 0.0f;
      #pragma unroll
      for (int ct = 0; ct < 8; ++ct) {
        float e = __expf(acc[rt][ct][i] - m);
        acc[rt][ct][i] = e;
        s += e;
      }
      sum4[rt][i] = s;
    }
  #pragma unroll
  for (int off = 1; off < 16; off <<= 1)
    #pragma unroll
    for (int rt = 0; rt < 4; ++rt)
      #pragma unroll
      for (int i = 0; i < 4; ++i)
        sum4[rt][i] += __shfl_xor(sum4[rt][i], off);
  if (c16 == 0) {
    #pragma unroll
    for (int rt = 0; rt < 4; ++rt)
      #pragma unroll
      for (int i = 0; i < 4; ++i)
        sm.red[w][rt * 16 + quad * 4 + i] = sum4[rt][i];
  }
  __syncthreads();
  if (tid < 64) {
    float s = 0.0f;
    #pragma unroll
    for (int w2 = 0; w2 < 8; ++w2) s += sm.red[w2][tid];
    sm.invrow[tid] = 1.0f / s;
  }
  __syncthreads();

  // ---- issue V span-0 prefetch now: stays in flight through phase 3 ----
  // Staging map: kap = key-in-span, dgb picks d-group; all 64 lanes of a wave
  // share one vt row per store -> conflict-free-ish writes.
  const int kap = tid & 127;
  const int dgb = tid >> 7;
  const int scol = (kap & 15) * 8 + (kap >> 4);   // sigma(kap)
  f32x4 pref[4];
  #pragma unroll
  for (int it = 0; it < 4; ++it) {
    int d0 = it * 16 + dgb * 4;
    pref[it] = *(const f32x4*)(Vg + (size_t)kap * DHEAD + d0);
  }

  // ---- phase 3: probs fp32 -> global (nontemporal); bf16 -> LDS permuted ----
  // pl[row][w*128 + c16*8 + ct] = P[row][w*128 + ct*16 + c16]  (= col sigma(k))
  #pragma unroll
  for (int rt = 0; rt < 4; ++rt) {
    #pragma unroll
    for (int i = 0; i < 4; ++i) {
      int row = rt * 16 + quad * 4 + i;
      float inv = sm.invrow[row];
      float* orow = out + ((size_t)bh * SLEN + qbase + row) * SLEN;
      bf16x8 pk;
      #pragma unroll
      for (int ct = 0; ct < 8; ++ct) {
        float p = acc[rt][ct][i] * inv;
        __builtin_nontemporal_store(p, &orow[w * 128 + ct * 16 + c16]);
        pk[ct] = (__bf16)p;
      }
      *(bf16x8*)&sm.pl[row][w * 128 + c16 * 8] = pk;   // one b128, bank-balanced
    }
  }

  // ---- phase 4: context = P @ V over 8 spans of 128 keys ----
  // Wave w -> row-tile (w&3), d-tiles {w>>2, (w>>2)+2}.
  // Both A (pl) and B (vt) are read at the SAME permuted k-slot columns, so
  // the MFMA contraction pairs matching keys.
  f32x4 ctx[2];
  {
    f32x4 z = {0.0f, 0.0f, 0.0f, 0.0f};
    ctx[0] = z; ctx[1] = z;
  }
  const int prt = w & 3;
  const int dtb = w >> 2;

  for (int sp = 0; sp < 8; ++sp) {
    __syncthreads();  // sp==0: pl complete; else: prior vt reads complete (+ pref landed)
    #pragma unroll
    for (int it = 0; it < 4; ++it) {
      int d0 = it * 16 + dgb * 4;
      #pragma unroll
      for (int j = 0; j < 4; ++j)
        sm.u.vt[d0 + j][scol] = (__bf16)pref[it][j];   // vt[d][sigma(k)]
    }
    __syncthreads();
    if (sp < 7) {     // prefetch AFTER the barrier: overlaps the MFMA block below
      #pragma unroll
      for (int it = 0; it < 4; ++it) {
        int d0 = it * 16 + dgb * 4;
        pref[it] = *(const f32x4*)(Vg + (size_t)((sp + 1) * 128 + kap) * DHEAD + d0);
      }
    }
    #pragma unroll
    for (int b2 = 0; b2 < 4; ++b2) {
      bf16x8 a = *(const bf16x8*)&sm.pl[prt * 16 + c16][sp * 128 + b2 * 32 + quad * 8];
      #pragma unroll
      for (int t2 = 0; t2 < 2; ++t2) {
        int dt = dtb + t2 * 2;
        bf16x8 b = *(const bf16x8*)&sm.u.vt[dt * 16 + c16][b2 * 32 + quad * 8];
        ctx[t2] = __builtin_amdgcn_mfma_f32_16x16x32_bf16(a, b, ctx[t2], 0, 0, 0);
      }
    }
  }

  // ---- write context (nontemporal) ----
  float* outC = out + (size_t)NBH * SLEN * SLEN;
  #pragma unroll
  for (int t2 = 0; t2 < 2; ++t2) {
    int dt = dtb + t2 * 2;
    #pragma unroll
    for (int i = 0; i < 4; ++i) {
      int row = prt * 16 + quad * 4 + i;
      __builtin_nontemporal_store(
          ctx[t2][i],
          &outC[((size_t)bh * SLEN + qbase + row) * DHEAD + dt * 16 + c16]);
    }
  }
}

extern "C" void kernel_launch(void* const* d_in, const int* in_sizes, int n_in,
                              void* d_out, int out_size, void* d_ws, size_t ws_size,
                              hipStream_t stream) {
  (void)in_sizes; (void)n_in; (void)d_ws; (void)ws_size; (void)out_size;
  const float* q = (const float*)d_in[0];
  const float* k = (const float*)d_in[1];
  const float* v = (const float*)d_in[2];
  const int* scale = (const int*)d_in[3];
  float* out = (float*)d_out;
  dim3 grid(SLEN / 64, NBH);
  dim3 block(512);
  hipLaunchKernelGGL(attn_fused, grid, block, 0, stream, q, k, v, scale, out);
}